// Round 1
// baseline (128.551 us; speedup 1.0000x reference)
//
#include <hip/hip_runtime.h>

// ElementalGTO fingerprint kernel for MI355X (gfx950).
// B=32 batches, N=128 atoms, N_SPECIES=4, N_GAUSS=20, LMAX=2 -> 10 ang comps,
// 10 mbody channels (4 species + 6 pairs), FP_SIZE = 3*10*20 = 600.
//
// Key algebraic simplification: pair channels are pure cross terms:
//   fpp[p] = sum_a 2*w_a * t[pi][a][g] * t[pj][a][g]
// so we only accumulate per-species t[s][a][g] (4*10*20 = 800 per atom).

#define NATOM 128

__device__ const float d_wA[10]  = {1.f,1.f,1.f,1.f,1.f,2.f,1.f,2.f,2.f,1.f};
__device__ const int   d_abase[3] = {0, 1, 4};
__device__ const int   d_acnt[3]  = {1, 3, 6};
__device__ const int   d_PI[6] = {0,0,0,1,1,2};
__device__ const int   d_PJ[6] = {1,2,3,2,3,3};

__global__ __launch_bounds__(128)
void egto_kernel(const float* __restrict__ coords,
                 const int*   __restrict__ charges,
                 const int*   __restrict__ natoms,
                 float*       __restrict__ out)
{
    __shared__ float sx[NATOM], sy[NATOM], sz[NATOM];
    __shared__ int   ssp[NATOM];
    __shared__ float sang[NATOM * 10];   // [m][a]
    __shared__ float srad[NATOM * 20];   // [m][g], rows 80B -> float2 aligned
    __shared__ float st[800];            // [a][g][s]

    const int bid = blockIdx.x;
    const int b = bid >> 7;
    const int n = bid & 127;
    const int t = threadIdx.x;

    // ---- load coords (SoA) + species index ----
    {
        const float* cb = coords + (size_t)b * NATOM * 3;
        sx[t] = cb[t * 3 + 0];
        sy[t] = cb[t * 3 + 1];
        sz[t] = cb[t * 3 + 2];
        int ch = charges[b * NATOM + t];
        ssp[t] = (ch == 1) ? 0 : (ch == 6) ? 1 : (ch == 7) ? 2 : 3;
    }
    __syncthreads();

    const int natom = natoms[b];
    const float xn = sx[n], yn = sy[n], zn = sz[n];

    // ---- per-neighbor angular + radial tables (thread t handles neighbor t) ----
    {
        const int m = t;
        float dx = xn - sx[m];
        float dy = yn - sy[m];
        float dz = zn - sz[m];
        float d2 = dx * dx + dy * dy + dz * dz;
        bool valid = (d2 < 36.0f) && (m != n) && (m < natom);
        float dist = sqrtf(valid ? d2 : 1.0f);
        float maskf = valid ? 1.0f : 0.0f;
        // 0.5*(cos(dist*pi/6)+1) * sqrt(2/pi) * mask
        float cutoff = 0.5f * (__cosf(dist * 0.52359877559829887f) + 1.0f);
        float cm = 0.79788456080286536f * cutoff * maskf;
        float invd = 1.0f / dist;
        float i2 = invd * invd;
        float i3 = i2 * invd;
        float i4 = i2 * i2;
        float* ap = &sang[m * 10];
        ap[0] = i2;
        ap[1] = i3 * dx;
        ap[2] = i3 * dy;
        ap[3] = i3 * dz;
        ap[4] = i4 * dx * dx;
        ap[5] = i4 * dx * dy;
        ap[6] = i4 * dy * dy;
        ap[7] = i4 * dx * dz;
        ap[8] = i4 * dy * dz;
        ap[9] = i4 * dz * dz;
        float* rp = &srad[m * 20];
#pragma unroll
        for (int g = 0; g < 20; ++g) {
            float dd = dist - 0.3f * (float)(g + 1);
            rp[g] = cm * __expf(-2.0f * dd * dd);
        }
    }
    __syncthreads();

    // ---- main accumulation: thread owns (a, g-pair); 100 active lanes ----
    if (t < 100) {
        const int a  = t / 10;
        const int gp = t - 10 * a;
        float a00 = 0.f, a01 = 0.f, a10 = 0.f, a11 = 0.f;
        float a20 = 0.f, a21 = 0.f, a30 = 0.f, a31 = 0.f;
        const float2* r2 = (const float2*)srad;
#pragma unroll 4
        for (int m = 0; m < NATOM; ++m) {
            float  av = sang[m * 10 + a];
            float2 rv = r2[m * 10 + gp];
            int s = __builtin_amdgcn_readfirstlane(ssp[m]);  // wave-uniform
            float p0 = av * rv.x;
            float p1 = av * rv.y;
            if (s == 0)      { a00 += p0; a01 += p1; }
            else if (s == 1) { a10 += p0; a11 += p1; }
            else if (s == 2) { a20 += p0; a21 += p1; }
            else             { a30 += p0; a31 += p1; }
        }
        float* tp = &st[(a * 20 + 2 * gp) * 4];
        tp[0] = a00; tp[1] = a10; tp[2] = a20; tp[3] = a30;
        tp[4] = a01; tp[5] = a11; tp[6] = a21; tp[7] = a31;
    }
    __syncthreads();

    // ---- epilogue: build 600 outputs ----
    const float avalid = (n < natom) ? 1.0f : 0.0f;
    float* ob = out + (size_t)bid * 600;
    for (int o = t; o < 600; o += 128) {
        int l = o / 200;
        int rem = o - 200 * l;
        int c = rem / 20;
        int g = rem - 20 * c;
        int ab = d_abase[l];
        int ac = d_acnt[l];
        float v = 0.0f;
        if (c < 4) {
            for (int k = 0; k < ac; ++k) {
                int a = ab + k;
                float tv = st[(a * 20 + g) * 4 + c];
                v += d_wA[a] * tv * tv;
            }
        } else {
            int p = c - 4;
            int pi = d_PI[p];
            int pj = d_PJ[p];
            for (int k = 0; k < ac; ++k) {
                int a = ab + k;
                float ti = st[(a * 20 + g) * 4 + pi];
                float tj = st[(a * 20 + g) * 4 + pj];
                v += 2.0f * d_wA[a] * ti * tj;
            }
        }
        ob[o] = v * avalid;
    }
}

extern "C" void kernel_launch(void* const* d_in, const int* in_sizes, int n_in,
                              void* d_out, int out_size, void* d_ws, size_t ws_size,
                              hipStream_t stream) {
    (void)n_in; (void)out_size; (void)d_ws; (void)ws_size;
    const float* coords  = (const float*)d_in[0];
    const int*   charges = (const int*)d_in[1];
    const int*   natoms  = (const int*)d_in[2];
    float* out = (float*)d_out;
    const int B = in_sizes[2];           // natom_counts has one entry per batch
    egto_kernel<<<dim3(B * NATOM), dim3(128), 0, stream>>>(coords, charges, natoms, out);
}

// Round 2
// 87.998 us; speedup vs baseline: 1.4608x; 1.4608x over previous
//
#include <hip/hip_runtime.h>

// ElementalGTO fingerprint kernel for MI355X (gfx950), round 2.
// B=32, N=128, 4 species, 20 gaussians, LMAX=2 -> 10 ang comps, FP_SIZE=600.
//
// Pair channels are cross terms: fpp[p] = sum_a 2*w_a*t[pi][a][g]*t[pj][a][g],
// so only per-species t[s][a][g] is accumulated.
//
// R2: neighbors are bucketed by species (ballot ranking, tables stored
// permuted) -> branch-free segmented inner loop: b32(ang) + b128(rad) + 4 FMA
// per neighbor. Padded LDS layouts make main-loop reads conflict-free.

#define NATOM 128

__device__ const float d_wA[10]   = {1.f,1.f,1.f,1.f,1.f,2.f,1.f,2.f,2.f,1.f};
__device__ const int   d_abase[3] = {0, 1, 4};
__device__ const int   d_acnt[3]  = {1, 3, 6};
__device__ const int   d_PI[6]    = {0,0,0,1,1,2};
__device__ const int   d_PJ[6]    = {1,2,3,2,3,3};

__global__ __launch_bounds__(128)
void egto_kernel(const float* __restrict__ coords,
                 const int*   __restrict__ charges,
                 const int*   __restrict__ natoms,
                 float*       __restrict__ out)
{
    __shared__ float sx[NATOM], sy[NATOM], sz[NATOM];
    __shared__ int   wcnt[2][4];
    __shared__ float sang[10 * 129];                 // [a][slot], pad 129: bank=(a+slot)%32
    __shared__ __align__(16) float srad[5 * 516];    // [gq][slot*4+j], pad 516 words
    __shared__ __align__(16) float st[1600];         // [w][(s*10+a)*20+g]

    const int bid  = blockIdx.x;
    const int b    = bid >> 7;
    const int n    = bid & 127;
    const int t    = threadIdx.x;
    const int wid  = t >> 6;
    const int lane = t & 63;

    // ---- load coords (SoA) + own neighbor's species ----
    const float* cb = coords + (size_t)b * NATOM * 3;
    const float cx = cb[t * 3 + 0];
    const float cy = cb[t * 3 + 1];
    const float cz = cb[t * 3 + 2];
    sx[t] = cx; sy[t] = cy; sz[t] = cz;
    const int ch = charges[b * NATOM + t];
    const int s  = (ch == 1) ? 0 : (ch == 6) ? 1 : (ch == 7) ? 2 : 3;

    // ---- ballot-based species ranking (per wave) ----
    const unsigned long long bm0 = __ballot(s == 0);
    const unsigned long long bm1 = __ballot(s == 1);
    const unsigned long long bm2 = __ballot(s == 2);
    const unsigned long long bm3 = __ballot(s == 3);
    const unsigned long long below = (1ull << lane) - 1ull;
    const unsigned long long msel = (s == 0) ? bm0 : (s == 1) ? bm1 : (s == 2) ? bm2 : bm3;
    const int rank_in_wave = __popcll(msel & below);
    if (lane == 0) {
        wcnt[wid][0] = __popcll(bm0);
        wcnt[wid][1] = __popcll(bm1);
        wcnt[wid][2] = __popcll(bm2);
        wcnt[wid][3] = __popcll(bm3);
    }
    __syncthreads();

    const int c0 = wcnt[0][0] + wcnt[1][0];
    const int c1 = wcnt[0][1] + wcnt[1][1];
    const int c2 = wcnt[0][2] + wcnt[1][2];
    const int b1 = c0, b2 = c0 + c1, b3 = c0 + c1 + c2;
    const int base_s = (s == 0) ? 0 : (s == 1) ? b1 : (s == 2) ? b2 : b3;
    const int slot = base_s + (wid ? wcnt[0][s] : 0) + rank_in_wave;

    const int natom = natoms[b];
    const float xn = sx[n], yn = sy[n], zn = sz[n];

    // ---- phase 1: per-neighbor ang/rad tables, written to permuted slot ----
    {
        const float dx = xn - cx;
        const float dy = yn - cy;
        const float dz = zn - cz;
        const float d2 = dx * dx + dy * dy + dz * dz;
        const bool valid = (d2 < 36.0f) && (t != n) && (t < natom);
        const float dist = sqrtf(valid ? d2 : 1.0f);
        const float maskf = valid ? 1.0f : 0.0f;
        const float cutoff = 0.5f * (__cosf(dist * 0.52359877559829887f) + 1.0f);
        const float cm = 0.79788456080286536f * cutoff * maskf;   // mask folded into radial
        const float invd = 1.0f / dist;
        const float i2 = invd * invd;
        const float i3 = i2 * invd;
        const float i4 = i2 * i2;
        sang[0 * 129 + slot] = i2;
        sang[1 * 129 + slot] = i3 * dx;
        sang[2 * 129 + slot] = i3 * dy;
        sang[3 * 129 + slot] = i3 * dz;
        sang[4 * 129 + slot] = i4 * dx * dx;
        sang[5 * 129 + slot] = i4 * dx * dy;
        sang[6 * 129 + slot] = i4 * dy * dy;
        sang[7 * 129 + slot] = i4 * dx * dz;
        sang[8 * 129 + slot] = i4 * dy * dz;
        sang[9 * 129 + slot] = i4 * dz * dz;
#pragma unroll
        for (int gq = 0; gq < 5; ++gq) {
            float4 r;
            float dd0 = dist - 0.3f * (float)(gq * 4 + 1);
            float dd1 = dist - 0.3f * (float)(gq * 4 + 2);
            float dd2 = dist - 0.3f * (float)(gq * 4 + 3);
            float dd3 = dist - 0.3f * (float)(gq * 4 + 4);
            r.x = cm * __expf(-2.0f * dd0 * dd0);
            r.y = cm * __expf(-2.0f * dd1 * dd1);
            r.z = cm * __expf(-2.0f * dd2 * dd2);
            r.w = cm * __expf(-2.0f * dd3 * dd3);
            *reinterpret_cast<float4*>(&srad[gq * 516 + slot * 4]) = r;
        }
    }
    __syncthreads();

    // ---- phase 2: branch-free segmented accumulation ----
    // lane -> (a, gq); 50 active lanes per wave; wave wid takes m = start+wid, +2.
    if (lane < 50) {
        const int a  = lane / 5;
        const int gq = lane - 5 * a;
        float4 acc0 = {0,0,0,0}, acc1 = {0,0,0,0}, acc2 = {0,0,0,0}, acc3 = {0,0,0,0};
        const float* angp = &sang[a * 129];
        const float* radp = &srad[gq * 516];

        auto seg = [&](int ms, int me, float4& acc) {
            for (int m = ms + wid; m < me; m += 2) {
                const float av = angp[m];
                const float4 rv = *reinterpret_cast<const float4*>(&radp[m * 4]);
                acc.x = fmaf(av, rv.x, acc.x);
                acc.y = fmaf(av, rv.y, acc.y);
                acc.z = fmaf(av, rv.z, acc.z);
                acc.w = fmaf(av, rv.w, acc.w);
            }
        };
        seg(0,  b1,  acc0);
        seg(b1, b2,  acc1);
        seg(b2, b3,  acc2);
        seg(b3, 128, acc3);

        float* stp = &st[wid * 800 + a * 20 + gq * 4];
        *reinterpret_cast<float4*>(&stp[0 * 200]) = acc0;
        *reinterpret_cast<float4*>(&stp[1 * 200]) = acc1;
        *reinterpret_cast<float4*>(&stp[2 * 200]) = acc2;
        *reinterpret_cast<float4*>(&stp[3 * 200]) = acc3;
    }
    __syncthreads();

    // ---- phase 3: epilogue, 600 outputs ----
    const float avalid = (n < natom) ? 1.0f : 0.0f;
    float* ob = out + (size_t)bid * 600;
    for (int o = t; o < 600; o += 128) {
        const int l   = o / 200;
        const int rem = o - 200 * l;
        const int c   = rem / 20;
        const int g   = rem - 20 * c;
        const int ab  = d_abase[l];
        const int ac  = d_acnt[l];
        float v = 0.0f;
        if (c < 4) {
            for (int k = 0; k < ac; ++k) {
                const int a = ab + k;
                const float tv = st[c * 200 + a * 20 + g] + st[800 + c * 200 + a * 20 + g];
                v = fmaf(d_wA[a] * tv, tv, v);
            }
        } else {
            const int p  = c - 4;
            const int pi = d_PI[p];
            const int pj = d_PJ[p];
            for (int k = 0; k < ac; ++k) {
                const int a = ab + k;
                const float ti = st[pi * 200 + a * 20 + g] + st[800 + pi * 200 + a * 20 + g];
                const float tj = st[pj * 200 + a * 20 + g] + st[800 + pj * 200 + a * 20 + g];
                v = fmaf(2.0f * d_wA[a] * ti, tj, v);
            }
        }
        ob[o] = v * avalid;
    }
}

extern "C" void kernel_launch(void* const* d_in, const int* in_sizes, int n_in,
                              void* d_out, int out_size, void* d_ws, size_t ws_size,
                              hipStream_t stream) {
    (void)n_in; (void)out_size; (void)d_ws; (void)ws_size;
    const float* coords  = (const float*)d_in[0];
    const int*   charges = (const int*)d_in[1];
    const int*   natoms  = (const int*)d_in[2];
    float* out = (float*)d_out;
    const int B = in_sizes[2];
    egto_kernel<<<dim3(B * NATOM), dim3(128), 0, stream>>>(coords, charges, natoms, out);
}

// Round 3
// 87.287 us; speedup vs baseline: 1.4728x; 1.0081x over previous
//
#include <hip/hip_runtime.h>

// ElementalGTO fingerprint kernel for MI355X (gfx950), round 3.
// B=32, N=128, 4 species, 20 gaussians, LMAX=2 -> 10 ang comps, FP_SIZE=600.
//
// Pair channels are cross terms: fpp[p] = sum_a 2*w_a*t[pi][a][g]*t[pj][a][g],
// so only per-species t[s][a][g] is accumulated.
//
// R3: (1) neighbors bucket-sorted by (valid ? species : discard) -> m-loop
// capped at round8(valid_count) (~2x fewer iters; cutoff+natom+self culling).
// (2) register blocking 2 ang x 4 gauss per lane (25 lanes/wave, waves split m
// by parity): b64 ang + b128 rad per m for 8 FMAs. (3) species separation via
// prefix snapshots at wave-uniform boundary indices (scalar compares only),
// keeping the inner loop fixed-trip and unrolled.

#define NATOM 128

__device__ const float d_wA[10]   = {1.f,1.f,1.f,1.f,1.f,2.f,1.f,2.f,2.f,1.f};
__device__ const int   d_abase[3] = {0, 1, 4};
__device__ const int   d_acnt[3]  = {1, 3, 6};
__device__ const int   d_PI[6]    = {0,0,0,1,1,2};
__device__ const int   d_PJ[6]    = {1,2,3,2,3,3};

__global__ __launch_bounds__(128)
void egto_kernel(const float* __restrict__ coords,
                 const int*   __restrict__ charges,
                 const int*   __restrict__ natoms,
                 float*       __restrict__ out)
{
    __shared__ float sx[NATOM], sy[NATOM], sz[NATOM];
    __shared__ int   wcnt[2][5];
    __shared__ __align__(16) float sang[NATOM * 10];  // [slot][a]
    __shared__ __align__(16) float srad[NATOM * 20];  // [slot][g]
    __shared__ __align__(16) float st[1600];          // [w][s*200 + a*20 + g]

    const int bid  = blockIdx.x;
    const int b    = bid >> 7;
    const int n    = bid & 127;
    const int t    = threadIdx.x;
    const int wid  = t >> 6;
    const int lane = t & 63;

    // ---- coords (SoA) + species ----
    const float* cb = coords + (size_t)b * NATOM * 3;
    const float cx = cb[t * 3 + 0];
    const float cy = cb[t * 3 + 1];
    const float cz = cb[t * 3 + 2];
    sx[t] = cx; sy[t] = cy; sz[t] = cz;
    const int ch = charges[b * NATOM + t];
    const int sp = (ch == 1) ? 0 : (ch == 6) ? 1 : (ch == 7) ? 2 : 3;
    const int natom = natoms[b];
    __syncthreads();

    const float xn = sx[n], yn = sy[n], zn = sz[n];
    const float dx = xn - cx;
    const float dy = yn - cy;
    const float dz = zn - cz;
    const float d2 = dx * dx + dy * dy + dz * dz;
    const bool  valid = (d2 < 36.0f) && (t != n) && (t < natom);
    const int   key = valid ? sp : 4;   // bucket 4 = discard

    // ---- 5-bucket ballot ranking (per wave) ----
    const unsigned long long m0 = __ballot(key == 0);
    const unsigned long long m1 = __ballot(key == 1);
    const unsigned long long m2 = __ballot(key == 2);
    const unsigned long long m3 = __ballot(key == 3);
    const unsigned long long below = (1ull << lane) - 1ull;
    const unsigned long long msel =
        (key == 0) ? m0 : (key == 1) ? m1 : (key == 2) ? m2 : (key == 3) ? m3
                    : ~(m0 | m1 | m2 | m3);
    const int rank = __popcll(msel & below);
    if (lane == 0) {
        const int n0 = __popcll(m0), n1 = __popcll(m1), n2 = __popcll(m2), n3 = __popcll(m3);
        wcnt[wid][0] = n0; wcnt[wid][1] = n1; wcnt[wid][2] = n2; wcnt[wid][3] = n3;
        wcnt[wid][4] = 64 - n0 - n1 - n2 - n3;
    }
    __syncthreads();

    const int c0 = wcnt[0][0] + wcnt[1][0];
    const int c1 = wcnt[0][1] + wcnt[1][1];
    const int c2 = wcnt[0][2] + wcnt[1][2];
    const int c3 = wcnt[0][3] + wcnt[1][3];
    const int B1 = c0, B2 = B1 + c1, B3 = B2 + c2, B4 = B3 + c3;  // B4 = valid total
    const int bstart = (key == 0) ? 0 : (key == 1) ? B1 : (key == 2) ? B2
                     : (key == 3) ? B3 : B4;
    const int slot = bstart + (wid ? wcnt[0][key] : 0) + rank;
    const int cap_r = (B4 + 7) & ~7;

    // ---- phase 1: per-neighbor tables at permuted slot ----
    if (valid) {
        const float dist = sqrtf(d2);
        const float cutoff = 0.5f * (__cosf(dist * 0.52359877559829887f) + 1.0f);
        const float cm = 0.79788456080286536f * cutoff;   // sqrt(2/pi)*cutoff
        const float invd = 1.0f / dist;
        const float i2 = invd * invd;
        const float i3 = i2 * invd;
        const float i4 = i2 * i2;
        float* ap = &sang[slot * 10];
        *reinterpret_cast<float2*>(&ap[0]) = make_float2(i2,        i3 * dx);
        *reinterpret_cast<float2*>(&ap[2]) = make_float2(i3 * dy,   i3 * dz);
        *reinterpret_cast<float2*>(&ap[4]) = make_float2(i4 * dx * dx, i4 * dx * dy);
        *reinterpret_cast<float2*>(&ap[6]) = make_float2(i4 * dy * dy, i4 * dx * dz);
        *reinterpret_cast<float2*>(&ap[8]) = make_float2(i4 * dy * dz, i4 * dz * dz);
        float* rp = &srad[slot * 20];
#pragma unroll
        for (int gq = 0; gq < 5; ++gq) {
            float dd0 = dist - 0.3f * (float)(gq * 4 + 1);
            float dd1 = dist - 0.3f * (float)(gq * 4 + 2);
            float dd2 = dist - 0.3f * (float)(gq * 4 + 3);
            float dd3 = dist - 0.3f * (float)(gq * 4 + 4);
            float4 r;
            r.x = cm * __expf(-2.0f * dd0 * dd0);
            r.y = cm * __expf(-2.0f * dd1 * dd1);
            r.z = cm * __expf(-2.0f * dd2 * dd2);
            r.w = cm * __expf(-2.0f * dd3 * dd3);
            *reinterpret_cast<float4*>(&rp[gq * 4]) = r;
        }
    } else if (slot < cap_r) {
        // inside the capped range: must be readable zeros
        float* ap = &sang[slot * 10];
        float* rp = &srad[slot * 20];
        const float2 z2 = make_float2(0.f, 0.f);
        const float4 z4 = make_float4(0.f, 0.f, 0.f, 0.f);
#pragma unroll
        for (int p = 0; p < 5; ++p) *reinterpret_cast<float2*>(&ap[p * 2]) = z2;
#pragma unroll
        for (int gq = 0; gq < 5; ++gq) *reinterpret_cast<float4*>(&rp[gq * 4]) = z4;
    }
    __syncthreads();

    // ---- phase 2: prefix accumulation with boundary snapshots ----
    if (lane < 25) {
        const int apair = lane / 5;        // a in {2*apair, 2*apair+1}
        const int gq    = lane - 5 * apair;
        const float* angp = &sang[2 * apair];
        const float* radp = &srad[4 * gq];

        // last m in this wave's parity sequence strictly below each boundary
        int t1 = B1 - 1; t1 -= (t1 - wid) & 1;
        int t2 = B2 - 1; t2 -= (t2 - wid) & 1;
        int t3 = B3 - 1; t3 -= (t3 - wid) & 1;

        float4 accA = {0,0,0,0}, accB = {0,0,0,0};
        float4 s1A  = {0,0,0,0}, s1B  = {0,0,0,0};
        float4 s2A  = {0,0,0,0}, s2B  = {0,0,0,0};
        float4 s3A  = {0,0,0,0}, s3B  = {0,0,0,0};

        auto body = [&](int m) {
            const float2 av = *reinterpret_cast<const float2*>(&angp[m * 10]);
            const float4 rv = *reinterpret_cast<const float4*>(&radp[m * 20]);
            accA.x = fmaf(av.x, rv.x, accA.x);
            accA.y = fmaf(av.x, rv.y, accA.y);
            accA.z = fmaf(av.x, rv.z, accA.z);
            accA.w = fmaf(av.x, rv.w, accA.w);
            accB.x = fmaf(av.y, rv.x, accB.x);
            accB.y = fmaf(av.y, rv.y, accB.y);
            accB.z = fmaf(av.y, rv.z, accB.z);
            accB.w = fmaf(av.y, rv.w, accB.w);
        };

        for (int i = 0; i < cap_r; i += 8) {
            const bool bhit = ((unsigned)(t1 - i) < 8u) |
                              ((unsigned)(t2 - i) < 8u) |
                              ((unsigned)(t3 - i) < 8u);
            if (!bhit) {
#pragma unroll
                for (int u = 0; u < 4; ++u) body(i + wid + 2 * u);
            } else {
#pragma unroll
                for (int u = 0; u < 4; ++u) {
                    const int m = i + wid + 2 * u;
                    body(m);
                    if (m == t1) { s1A = accA; s1B = accB; }
                    if (m == t2) { s2A = accA; s2B = accB; }
                    if (m == t3) { s3A = accA; s3B = accB; }
                }
            }
        }

        // segment sums from prefix snapshots; store per-wave partials
        float* stp = &st[wid * 800 + (2 * apair) * 20 + gq * 4];
        const float4 v0A = s1A;
        const float4 v0B = s1B;
        float4 v1A, v1B, v2A, v2B, v3A, v3B;
        v1A.x = s2A.x - s1A.x; v1A.y = s2A.y - s1A.y; v1A.z = s2A.z - s1A.z; v1A.w = s2A.w - s1A.w;
        v1B.x = s2B.x - s1B.x; v1B.y = s2B.y - s1B.y; v1B.z = s2B.z - s1B.z; v1B.w = s2B.w - s1B.w;
        v2A.x = s3A.x - s2A.x; v2A.y = s3A.y - s2A.y; v2A.z = s3A.z - s2A.z; v2A.w = s3A.w - s2A.w;
        v2B.x = s3B.x - s2B.x; v2B.y = s3B.y - s2B.y; v2B.z = s3B.z - s2B.z; v2B.w = s3B.w - s2B.w;
        v3A.x = accA.x - s3A.x; v3A.y = accA.y - s3A.y; v3A.z = accA.z - s3A.z; v3A.w = accA.w - s3A.w;
        v3B.x = accB.x - s3B.x; v3B.y = accB.y - s3B.y; v3B.z = accB.z - s3B.z; v3B.w = accB.w - s3B.w;
        *reinterpret_cast<float4*>(&stp[0 * 200 +  0]) = v0A;
        *reinterpret_cast<float4*>(&stp[0 * 200 + 20]) = v0B;
        *reinterpret_cast<float4*>(&stp[1 * 200 +  0]) = v1A;
        *reinterpret_cast<float4*>(&stp[1 * 200 + 20]) = v1B;
        *reinterpret_cast<float4*>(&stp[2 * 200 +  0]) = v2A;
        *reinterpret_cast<float4*>(&stp[2 * 200 + 20]) = v2B;
        *reinterpret_cast<float4*>(&stp[3 * 200 +  0]) = v3A;
        *reinterpret_cast<float4*>(&stp[3 * 200 + 20]) = v3B;
    }
    __syncthreads();

    // ---- phase 3: epilogue, 600 outputs ----
    const float avalid = (n < natom) ? 1.0f : 0.0f;
    float* ob = out + (size_t)bid * 600;
    for (int o = t; o < 600; o += 128) {
        const int l   = o / 200;
        const int rem = o - 200 * l;
        const int c   = rem / 20;
        const int g   = rem - 20 * c;
        const int ab  = d_abase[l];
        const int ac  = d_acnt[l];
        float v = 0.0f;
        if (c < 4) {
            for (int k = 0; k < ac; ++k) {
                const int a = ab + k;
                const float tv = st[c * 200 + a * 20 + g] + st[800 + c * 200 + a * 20 + g];
                v = fmaf(d_wA[a] * tv, tv, v);
            }
        } else {
            const int p  = c - 4;
            const int pi = d_PI[p];
            const int pj = d_PJ[p];
            for (int k = 0; k < ac; ++k) {
                const int a = ab + k;
                const float ti = st[pi * 200 + a * 20 + g] + st[800 + pi * 200 + a * 20 + g];
                const float tj = st[pj * 200 + a * 20 + g] + st[800 + pj * 200 + a * 20 + g];
                v = fmaf(2.0f * d_wA[a] * ti, tj, v);
            }
        }
        ob[o] = v * avalid;
    }
}

extern "C" void kernel_launch(void* const* d_in, const int* in_sizes, int n_in,
                              void* d_out, int out_size, void* d_ws, size_t ws_size,
                              hipStream_t stream) {
    (void)n_in; (void)out_size; (void)d_ws; (void)ws_size;
    const float* coords  = (const float*)d_in[0];
    const int*   charges = (const int*)d_in[1];
    const int*   natoms  = (const int*)d_in[2];
    float* out = (float*)d_out;
    const int B = in_sizes[2];
    egto_kernel<<<dim3(B * NATOM), dim3(128), 0, stream>>>(coords, charges, natoms, out);
}